// Round 2
// baseline (7946.165 us; speedup 1.0000x reference)
//
#include <hip/hip_runtime.h>
#include <math.h>

// Problem constants (match reference)
#define B_   1024
#define NC   100
#define NN   101          // N = NC + 1
#define E_   128
#define H_   8
#define T_   202          // 2*N
#define NEGV -1.0e9

// ---------------------------------------------------------------------------
// kernel 0: M[g][e] = sum_f Wk2[g][f] * Wout[e][f]  (fp64), 128x128 into d_ws
// ---------------------------------------------------------------------------
__global__ void k_weights(const float* __restrict__ Wk2,
                          const float* __restrict__ Wout,
                          double* __restrict__ M) {
    int g = blockIdx.x;   // 0..127
    int e = threadIdx.x;  // 0..127
    const float* w2 = Wk2 + g * E_;
    const float* wo = Wout + e * E_;
    double acc = 0.0;
#pragma unroll 8
    for (int f = 0; f < E_; ++f) acc += (double)w2[f] * (double)wo[f];
    M[g * E_ + e] = acc;
}

// ---------------------------------------------------------------------------
// Main decoder: one block per batch element, 512 threads (8 waves).
// Decision path entirely in fp64; state (D, masks) in fp32 bit-matching ref.
// LDS: V[101][128] fp64 (~103 KB) + scratch (~16 KB).
// Registers: K1, K2t, Kstep chunks (32 doubles each) per thread.
// ---------------------------------------------------------------------------
__global__ __launch_bounds__(512, 1)
void k_decode(const float* __restrict__ depot_xy,
              const float* __restrict__ customer_xy,
              const float* __restrict__ demand,
              const float* __restrict__ node_emb,
              const float* __restrict__ graph_emb,
              const float* __restrict__ Wk1,
              const float* __restrict__ Wv,
              const float* __restrict__ Wq_fixed,
              const float* __restrict__ Wq_step,
              const double* __restrict__ M,     // Wk2 @ Wout^T (fp64) from ws
              float* __restrict__ out)          // [2*B]: cost then ll
{
    __shared__ double sV [NN * E_];     // V rows (fp64)
    __shared__ double sQ1G[E_];         // phase A2: scaled Q1; phase C2: glimpse
    __shared__ double sKsel[E_];        // broadcast Kstep row of prev node
    __shared__ double sScore[H_ * NN];  // scores -> exp(scores-max)
    __shared__ double sPart[4 * E_];    // 4-chunk partials (glimpse, logits)
    __shared__ double sQfix[E_];
    __shared__ double sWqD[E_];         // last row of Wq_step (the D column)
    __shared__ double sInvS[H_];
    __shared__ float  sCoord[2 * NN];   // interleaved x,y; index 0 = depot
    __shared__ float  sDem[NC];
    __shared__ float  sD;
    __shared__ double sCost, sLL;
    __shared__ float  sPosX, sPosY;
    __shared__ int    sPrev, sMaskDepot;
    __shared__ unsigned long long sVis0, sVis1;

    const int b      = blockIdx.x;
    const int tid    = threadIdx.x;
    const int k_lane = tid & 127;              // node owned by this thread
    const int q2     = tid >> 7;               // 0..3, uniform per wave-pair
    const int e0     = __builtin_amdgcn_readfirstlane(q2) * 32; // col chunk base

    const float* emb = node_emb + (size_t)b * NN * E_;
    const double inv_sqrt_e = 0.08838834764831845;   // 1/sqrt(128)

    // ---------------- prologue ----------------
    if (tid < E_) {
        const float* ge = graph_emb + (size_t)b * E_;
        double acc = 0.0;
        for (int g = 0; g < E_; ++g)
            acc += (double)ge[g] * (double)Wq_fixed[g * E_ + tid];
        sQfix[tid] = acc;
        sWqD[tid]  = (double)Wq_step[128 * E_ + tid];
    }
    if (tid < 2 * NN) {
        int k = tid >> 1, xy = tid & 1;
        sCoord[tid] = (k == 0) ? depot_xy[(size_t)b * 2 + xy]
                               : customer_xy[((size_t)b * NC + (k - 1)) * 2 + xy];
    }
    if (tid < NC) sDem[tid] = demand[(size_t)b * NC + tid];
    if (tid == 0) {
        sD = 1.f; sPrev = 0; sVis0 = 0ull; sVis1 = 0ull;
        sMaskDepot = 1; sCost = 0.0; sLL = 0.0;
        sPosX = depot_xy[(size_t)b * 2 + 0];
        sPosY = depot_xy[(size_t)b * 2 + 1];
    }

    // V into LDS (fp64 accumulate over emb row x Wv columns)
    for (int idx = tid; idx < NN * 32; idx += 512) {
        int k  = idx >> 5;
        int e4 = (idx & 31) * 4;
        const float* er = emb + (size_t)k * E_;
        double a0 = 0.0, a1 = 0.0, a2 = 0.0, a3 = 0.0;
        for (int g = 0; g < E_; ++g) {
            double eg = (double)er[g];
            float4 wv = *(const float4*)(Wv + (size_t)g * E_ + e4);
            a0 += eg * (double)wv.x; a1 += eg * (double)wv.y;
            a2 += eg * (double)wv.z; a3 += eg * (double)wv.w;
        }
        sV[(size_t)k * E_ + e4 + 0] = a0;
        sV[(size_t)k * E_ + e4 + 1] = a1;
        sV[(size_t)k * E_ + e4 + 2] = a2;
        sV[(size_t)k * E_ + e4 + 3] = a3;
    }

    // K1, K2t, Kstep 32-column chunks into registers (fp64)
    double rK1[32], rK2[32], rKs[32];
#pragma unroll
    for (int j = 0; j < 32; ++j) { rK1[j] = 0.0; rK2[j] = 0.0; rKs[j] = 0.0; }
    if (k_lane < NN) {
        const float* er = emb + (size_t)k_lane * E_;
        for (int g = 0; g < E_; ++g) {
            double eg = (double)er[g];
            const float*  w1 = Wk1     + (size_t)g * E_ + e0;
            const float*  wq = Wq_step + (size_t)g * E_ + e0;
            const double* mm = M       + (size_t)g * E_ + e0;
#pragma unroll
            for (int j = 0; j < 32; ++j) {
                rK1[j] += eg * (double)w1[j];
                rKs[j] += eg * (double)wq[j];
                rK2[j] += eg * mm[j];
            }
        }
    }
    __syncthreads();

    // ---------------- sequential decode loop ----------------
    for (int t = 0; t < T_; ++t) {
        // A1: owners of row sPrev broadcast their Kstep chunk
        if (k_lane == sPrev) {
#pragma unroll
            for (int j = 0; j < 32; ++j) sKsel[e0 + j] = rKs[j];
        }
        __syncthreads();

        // A2: Q1 scaled by 1/sqrt(DH)=0.25 (threads 0..127)
        if (tid < E_) {
            double q = sQfix[tid] + sKsel[tid] + (double)sD * sWqD[tid];
            sQ1G[tid] = q * 0.25;
        }
        __syncthreads();

        // B: per-(k, head-pair) scores; masked -> NEG
        if (k_lane < NN) {
            bool mk;
            if (k_lane == 0) mk = (sMaskDepot != 0);
            else {
                int c = k_lane - 1;
                bool vis = (c < 64) ? ((sVis0 >> c) & 1ull)
                                    : ((sVis1 >> (c - 64)) & 1ull);
                mk = vis || (sDem[c] > sD);
            }
            int h0 = q2 * 2, h1 = h0 + 1;
            if (mk) {
                sScore[h0 * NN + k_lane] = NEGV;
                sScore[h1 * NN + k_lane] = NEGV;
            } else {
                double s0 = 0.0, s1 = 0.0;
#pragma unroll
                for (int j = 0; j < 16; ++j)  s0 += rK1[j]      * sQ1G[e0 + j];
#pragma unroll
                for (int j = 0; j < 16; ++j)  s1 += rK1[16 + j] * sQ1G[e0 + 16 + j];
                sScore[h0 * NN + k_lane] = s0;
                sScore[h1 * NN + k_lane] = s1;
            }
        }
        __syncthreads();

        // B2: per-head softmax, one wave per head (no barrier internally)
        {
            int h = tid >> 6;        // 0..7
            int lane = tid & 63;
            int kA = lane, kB = lane + 64;
            double v1 = sScore[h * NN + kA];
            double v2 = (kB < NN) ? sScore[h * NN + kB] : -1.0e300;
            double m = fmax(v1, v2);
#pragma unroll
            for (int off = 32; off > 0; off >>= 1)
                m = fmax(m, __shfl_xor(m, off));
            double ex1 = exp(v1 - m);
            double ex2 = (kB < NN) ? exp(v2 - m) : 0.0;
            sScore[h * NN + kA] = ex1;
            if (kB < NN) sScore[h * NN + kB] = ex2;
            double s = ex1 + ex2;
#pragma unroll
            for (int off = 32; off > 0; off >>= 1)
                s += __shfl_xor(s, off);
            if (lane == 0) sInvS[h] = 1.0 / s;
        }
        __syncthreads();

        // C: glimpse partials over 4 k-chunks
        {
            int e  = k_lane;                 // 0..127
            int kb = q2 * 26;
            int ke = (q2 == 3) ? NN : kb + 26;
            int h  = e >> 4;
            double p = 0.0;
            for (int k = kb; k < ke; ++k)
                p += sScore[h * NN + k] * sV[(size_t)k * E_ + e];
            sPart[q2 * E_ + e] = p;
        }
        __syncthreads();

        // C2: combine partials, normalize -> glimpse into sQ1G
        if (tid < E_) {
            double gl = (sPart[tid] + sPart[E_ + tid] + sPart[2 * E_ + tid]
                         + sPart[3 * E_ + tid]) * sInvS[tid >> 4];
            sQ1G[tid] = gl;
        }
        __syncthreads();

        // D: logits partials (glimpse . K2t chunk)
        if (k_lane < NN) {
            double p = 0.0;
#pragma unroll
            for (int j = 0; j < 32; ++j) p += rK2[j] * sQ1G[e0 + j];
            sPart[q2 * E_ + k_lane] = p;
        }
        __syncthreads();

        // E: wave 0 — pre-tanh argmax (first-index ties), then LL via tanh/lse
        if (tid < 64) {
            int kA = tid, kB = tid + 64;
            double x1, x2 = 0.0;
            bool mk1, mk2 = true;
            {
                x1 = (sPart[kA] + sPart[E_ + kA] + sPart[2 * E_ + kA]
                      + sPart[3 * E_ + kA]) * inv_sqrt_e;
                if (kA == 0) mk1 = (sMaskDepot != 0);
                else {
                    int c = kA - 1;
                    bool vis = (c < 64) ? ((sVis0 >> c) & 1ull) : ((sVis1 >> (c - 64)) & 1ull);
                    mk1 = vis || (sDem[c] > sD);
                }
            }
            if (kB < NN) {
                x2 = (sPart[kB] + sPart[E_ + kB] + sPart[2 * E_ + kB]
                      + sPart[3 * E_ + kB]) * inv_sqrt_e;
                int c = kB - 1;
                bool vis = (c < 64) ? ((sVis0 >> c) & 1ull) : ((sVis1 >> (c - 64)) & 1ull);
                mk2 = vis || (sDem[c] > sD);
            }
            // argmax on pre-tanh x (monotone in logits), masked -> -inf-ish
            double a1 = mk1 ? -1.0e300 : x1;
            double a2 = mk2 ? -1.0e300 : x2;
            double mv; int mi;
            if (a1 >= a2) { mv = a1; mi = kA; } else { mv = a2; mi = kB; }
#pragma unroll
            for (int off = 32; off > 0; off >>= 1) {
                double ov = __shfl_xor(mv, off);
                int    oi = __shfl_xor(mi, off);
                if (ov > mv || (ov == mv && oi < mi)) { mv = ov; mi = oi; }
            }
            // logits for LL (masked = NEG, matching reference values)
            double lmax = 10.0 * tanh(mv);
            double l1 = mk1 ? NEGV : 10.0 * tanh(x1);
            double l2 = (kB < NN) ? (mk2 ? NEGV : 10.0 * tanh(x2)) : 0.0;
            double s = exp(l1 - lmax) + ((kB < NN) ? exp(l2 - lmax) : 0.0);
#pragma unroll
            for (int off = 32; off > 0; off >>= 1)
                s += __shfl_xor(s, off);

            if (tid == 0) {
                int nxt = mi;
                sLL += -log(s);           // log_p[argmax] = -log(sum exp(l - lmax))
                bool isdep = (nxt == 0);
                if (isdep) {
                    sD = 1.0f;
                } else {
                    int c = nxt - 1;
                    sD = sD - sDem[c];    // fp32, bit-matching reference
                    if (c < 64) sVis0 |= (1ull << c);
                    else        sVis1 |= (1ull << (c - 64));
                }
                bool allv = (sVis0 == 0xFFFFFFFFFFFFFFFFull) &&
                            (sVis1 == 0x0000000FFFFFFFFFull);   // 100 bits
                sMaskDepot = (isdep && !allv) ? 1 : 0;
                sPrev = nxt;
                float cx = sCoord[2 * nxt], cy = sCoord[2 * nxt + 1];
                double dx = (double)cx - (double)sPosX;
                double dy = (double)cy - (double)sPosY;
                sCost += sqrt(dx * dx + dy * dy + 1e-10);
                sPosX = cx; sPosY = cy;
            }
        }
        __syncthreads();
    }

    if (tid == 0) {
        double dx = (double)sCoord[0] - (double)sPosX;
        double dy = (double)sCoord[1] - (double)sPosY;
        out[b]      = (float)(sCost + sqrt(dx * dx + dy * dy + 1e-10));
        out[B_ + b] = (float)sLL;
    }
}

// ---------------------------------------------------------------------------
extern "C" void kernel_launch(void* const* d_in, const int* in_sizes, int n_in,
                              void* d_out, int out_size, void* d_ws, size_t ws_size,
                              hipStream_t stream) {
    const float* depot = (const float*)d_in[0];
    const float* cust  = (const float*)d_in[1];
    const float* dem   = (const float*)d_in[2];
    const float* nemb  = (const float*)d_in[3];
    const float* gemb  = (const float*)d_in[4];
    const float* Wk1   = (const float*)d_in[5];
    const float* Wv    = (const float*)d_in[6];
    const float* Wk2   = (const float*)d_in[7];
    const float* Wqf   = (const float*)d_in[8];
    const float* Wout  = (const float*)d_in[9];
    const float* Wqs   = (const float*)d_in[10];
    float*  out = (float*)d_out;
    double* M   = (double*)d_ws;   // 128*128 doubles = 128 KB

    k_weights<<<dim3(128), dim3(128), 0, stream>>>(Wk2, Wout, M);
    k_decode <<<dim3(B_),  dim3(512), 0, stream>>>(depot, cust, dem, nemb, gemb,
                                                   Wk1, Wv, Wqf, Wqs, M, out);
}